// Round 2
// baseline (111.553 us; speedup 1.0000x reference)
//
#include <hip/hip_runtime.h>

#define HH 100
#define WW 100
#define NN 10000
#define G  10          // i's per block; G | 100 so a block's i's share a row
#define BLK 256

__global__ __launch_bounds__(BLK) void HausdorffDistance_28406913696124_kernel(
    const float* __restrict__ prob, const float* __restrict__ gt,
    float* __restrict__ out)
{
    __shared__ float s_py[NN];      // 40 KB: binarized gt map
    __shared__ float sS1[G], sS2[G];

    const int tid = threadIdx.x;
    if (tid < G) { sS1[tid] = 0.0f; sS2[tid] = 0.0f; }

    // stage py = (gt >= 0.5) into LDS (coalesced, ~40 iterations)
    for (int j = tid; j < NN; j += BLK)
        s_py[j] = (gt[j] >= 0.5f) ? 1.0f : 0.0f;
    __syncthreads();

    const int i0 = blockIdx.x * G;              // G | 100 -> same row for all g
    const float ri = (float)(i0 / WW);
    const float c0 = (float)(i0 % WW);

    float s1[G], s2[G];
#pragma unroll
    for (int g = 0; g < G; ++g) { s1[g] = 0.0f; s2[g] = 0.0f; }

    float jf = (float)tid;
    for (int j = tid; j < NN; j += BLK) {
        // row/col of j via float trick: exact for j < 10000
        float af  = floorf(fmaf(jf, 0.01f, 5.0e-4f));   // a = j / 100
        float bf  = fmaf(af, -100.0f, jf);              // b = j % 100 (exact int)
        float py  = s_py[j];                            // stride-256 -> conflict-free
        float dx  = ri - af;
        float dx2 = dx * dx;                            // shared across all G cols
        float dyb = c0 - bf;
#pragma unroll
        for (int g = 0; g < G; ++g) {
            float dy = dyb + (float)g;                  // inline-const add
            float d2 = fmaf(dy, dy, dx2);               // exact small integer
            float d  = sqrtf(d2);                       // v_sqrt_f32
            s1[g] += d;
            s2[g]  = fmaf(d, py, s2[g]);
        }
        jf += (float)BLK;
    }

    // 64-lane butterfly reduction per accumulator
#pragma unroll
    for (int g = 0; g < G; ++g) {
#pragma unroll
        for (int off = 32; off >= 1; off >>= 1) {
            s1[g] += __shfl_xor(s1[g], off, 64);
            s2[g] += __shfl_xor(s2[g], off, 64);
        }
    }
    if ((tid & 63) == 0) {          // lane 0 of each of 4 waves
#pragma unroll
        for (int g = 0; g < G; ++g) {
            atomicAdd(&sS1[g], s1[g]);
            atomicAdd(&sS2[g], s2[g]);
        }
    }
    __syncthreads();

    if (tid == 0) {
        float acc = 0.0f;
#pragma unroll
        for (int g = 0; g < G; ++g) {
            float px = (prob[i0 + g] >= 0.5f) ? 1.0f : 0.0f;
            acc += fabsf(px * sS1[g] - sS2[g]);
        }
        // loss_i = |px*S1 - S2| / N ; output = mean_i loss_i = sum / N^2
        atomicAdd(out, acc * 1.0e-8f);
    }
}

extern "C" void kernel_launch(void* const* d_in, const int* in_sizes, int n_in,
                              void* d_out, int out_size, void* d_ws, size_t ws_size,
                              hipStream_t stream) {
    const float* prob = (const float*)d_in[0];   // prob_map [1,100,100] fp32
    const float* gt   = (const float*)d_in[1];   // gt_map   [1,100,100] fp32
    float* out = (float*)d_out;                  // scalar fp32

    // d_out is re-poisoned to 0xAA before every launch: zero it (capture-safe)
    (void)hipMemsetAsync(out, 0, sizeof(float), stream);

    const int nblocks = NN / G;                  // 1000
    HausdorffDistance_28406913696124_kernel<<<nblocks, BLK, 0, stream>>>(prob, gt, out);
}

// Round 3
// 79.319 us; speedup vs baseline: 1.4064x; 1.4064x over previous
//
#include <hip/hip_runtime.h>

#define NN  10000
#define G   10          // i's per block; G | 100 so a block's i's share a row
#define BLK 256
#define NG  2500        // NN/4 groups of 4 consecutive j (4 | 100 -> same row)

#if __has_builtin(__builtin_amdgcn_sqrtf)
#define FSQRT(x) __builtin_amdgcn_sqrtf(x)   // raw v_sqrt_f32, ±1 ulp
#else
#define FSQRT(x) sqrtf(x)
#endif

__global__ __launch_bounds__(BLK) void HausdorffDistance_28406913696124_kernel(
    const float* __restrict__ prob, const float* __restrict__ gt,
    float* __restrict__ out)
{
    __shared__ float s_py[NN];      // 40 KB: binarized gt map
    __shared__ float sS1[G], sS2[G];

    const int tid = threadIdx.x;
    if (tid < G) { sS1[tid] = 0.0f; sS2[tid] = 0.0f; }

    // stage py = (gt >= 0.5) into LDS, vectorized float4
    const float4* gt4 = (const float4*)gt;
    float4* s_py4 = (float4*)s_py;
    for (int m = tid; m < NG; m += BLK) {
        float4 v = gt4[m];
        float4 w;
        w.x = (v.x >= 0.5f) ? 1.0f : 0.0f;
        w.y = (v.y >= 0.5f) ? 1.0f : 0.0f;
        w.z = (v.z >= 0.5f) ? 1.0f : 0.0f;
        w.w = (v.w >= 0.5f) ? 1.0f : 0.0f;
        s_py4[m] = w;
    }
    __syncthreads();

    const int i0 = blockIdx.x * G;              // G | 100 -> same row for all g
    const float ri = (float)(i0 / 100);
    const float c0 = (float)(i0 % 100);

    float s1[G], s2[G];
#pragma unroll
    for (int g = 0; g < G; ++g) { s1[g] = 0.0f; s2[g] = 0.0f; }

    for (int m = tid; m < NG; m += BLK) {
        float4 py4 = s_py4[m];                  // ds_read_b128
        float j0f = (float)(4 * m);
        // row/col of j0 via float trick: exact for j < 10000
        float af  = floorf(fmaf(j0f, 0.01f, 5.0e-4f)); // a = j0 / 100
        float b0  = fmaf(af, -100.0f, j0f);            // b = j0 % 100
        float dx  = ri - af;
        float dx2 = dx * dx;                    // shared across all 40 pairs
        float dyb = c0 - b0;
        const float pys[4] = {py4.x, py4.y, py4.z, py4.w};
#pragma unroll
        for (int q = 0; q < 4; ++q) {
            float dq = dyb - (float)q;
            float py = pys[q];
#pragma unroll
            for (int g = 0; g < G; ++g) {
                float dy = dq + (float)g;       // inline-const add
                float d  = FSQRT(fmaf(dy, dy, dx2));
                s1[g] += d;
                s2[g]  = fmaf(d, py, s2[g]);
            }
        }
    }

    // 64-lane butterfly reduction per accumulator
#pragma unroll
    for (int g = 0; g < G; ++g) {
#pragma unroll
        for (int off = 32; off >= 1; off >>= 1) {
            s1[g] += __shfl_xor(s1[g], off, 64);
            s2[g] += __shfl_xor(s2[g], off, 64);
        }
    }
    if ((tid & 63) == 0) {          // lane 0 of each of 4 waves
#pragma unroll
        for (int g = 0; g < G; ++g) {
            atomicAdd(&sS1[g], s1[g]);
            atomicAdd(&sS2[g], s2[g]);
        }
    }
    __syncthreads();

    if (tid == 0) {
        float acc = 0.0f;
#pragma unroll
        for (int g = 0; g < G; ++g) {
            float px = (prob[i0 + g] >= 0.5f) ? 1.0f : 0.0f;
            acc += fabsf(px * sS1[g] - sS2[g]);
        }
        // loss_i = |px*S1 - S2| / N ; output = mean_i loss_i = sum / N^2
        atomicAdd(out, acc * 1.0e-8f);
    }
}

extern "C" void kernel_launch(void* const* d_in, const int* in_sizes, int n_in,
                              void* d_out, int out_size, void* d_ws, size_t ws_size,
                              hipStream_t stream) {
    const float* prob = (const float*)d_in[0];   // prob_map [1,100,100] fp32
    const float* gt   = (const float*)d_in[1];   // gt_map   [1,100,100] fp32
    float* out = (float*)d_out;                  // scalar fp32

    // d_out is re-poisoned to 0xAA before every launch: zero it (capture-safe)
    (void)hipMemsetAsync(out, 0, sizeof(float), stream);

    const int nblocks = NN / G;                  // 1000
    HausdorffDistance_28406913696124_kernel<<<nblocks, BLK, 0, stream>>>(prob, gt, out);
}